// Round 5
// baseline (159.529 us; speedup 1.0000x reference)
//
#include <hip/hip_runtime.h>
#include <math.h>

#define CCH 256
#define HW  9216
#define CW  24576
#define TWO_PI 6.28318530717958647692f

typedef __attribute__((ext_vector_type(8))) short short8;
typedef __attribute__((ext_vector_type(4))) float f32x4;

__device__ inline unsigned short f2bf(float f) {
    unsigned u = __float_as_uint(f);
    unsigned r = (u + 0x7FFFu + ((u >> 16) & 1u)) >> 16;   // RNE
    return (unsigned short)r;
}

// ---------------- K_front: fused transp(+per-channel minmax) and wconv ----------------
// blocks [0,576): fuse -> bf16 tiles [ptile][kc][n]  + per-channel |x| min/max atomics
// blocks [576,640): Wq/Wv -> bf16 tiles [ot][kc][m]
// MnMx[c]      = raw bits of max|x|  (signed atomicMax; 0xAA poison is negative -> safe)
// MnMx[256+c]  = raw bits of min|x|  (unsigned atomicMin; 0xAAAAAAAA > any float bits -> safe)
__global__ __launch_bounds__(256) void k_front(const float* __restrict__ x,
                                               const float* __restrict__ Wq,
                                               const float* __restrict__ Wv,
                                               short8* __restrict__ Wqt,
                                               short8* __restrict__ Wvt,
                                               unsigned short* __restrict__ XTv,
                                               unsigned* __restrict__ MnMx) {
    __shared__ unsigned short lt[64][66];
    int bid = blockIdx.x;
    int t = threadIdx.x;
    if (bid < 576) {
        int ptile = bid % 144, ct = bid / 144;
        int tx = t & 63, tw = t >> 6;
        int p0 = ptile * 64, c0 = ct * 64;
        #pragma unroll
        for (int i = 0; i < 16; ++i) {
            int row = tw * 16 + i;                    // channel c0+row, same for whole wave
            float v = x[(size_t)(c0 + row) * HW + p0 + tx];
            lt[row][tx] = f2bf(v);
            float a = fabsf(v);
            float lo = a, hi = a;
            #pragma unroll
            for (int d = 32; d; d >>= 1) {
                lo = fminf(lo, __shfl_xor(lo, d, 64));
                hi = fmaxf(hi, __shfl_xor(hi, d, 64));
            }
            if (tx == 0) {
                atomicMax((int*)&MnMx[c0 + row], (int)__float_as_uint(hi));
                atomicMin(&MnMx[256 + c0 + row], __float_as_uint(lo));
            }
        }
        __syncthreads();
        short8* dst = (short8*)XTv;
        #pragma unroll
        for (int ch = 0; ch < 2; ++ch) {
            int lc = ch * 256 + t;
            int kcg = lc >> 6, n = lc & 63;
            short8 v;
            #pragma unroll
            for (int e = 0; e < 8; ++e) v[e] = (short)lt[kcg * 8 + e][n];
            dst[ptile * 2048 + (ct * 8 + kcg) * 64 + n] = v;
        }
    } else {
        int widx = bid - 576;                         // 0..63
        const float* src = (widx >= 32) ? Wv : Wq;
        short8* dst = (widx >= 32) ? Wvt : Wqt;
        int cidx = (widx & 31) * 256 + t;             // 0..8191
        int ot = cidx >> 11, kc = (cidx >> 6) & 31, m = cidx & 63;
        const float* s = src + (ot * 64 + m) * 256 + kc * 8;
        short8 v;
        #pragma unroll
        for (int e = 0; e < 8; ++e) v[e] = (short)f2bf(s[e]);
        dst[cidx] = v;
    }
}

// ---------------- K1: 16 DFT coefficients per channel ----------------
// Kept freqs (un-fftshifted): ky,kx in {-2,-1,0,1}. Writes Fg[c*32 + 2*(ky*4+kx) + {re,im}].
__global__ __launch_bounds__(768) void k_dft(const float* __restrict__ x,
                                             const unsigned* __restrict__ MnMx,
                                             float* __restrict__ Fg) {
    __shared__ float cs[96][2];
    __shared__ float Gp[8][96][5];   // per-y-chunk partial column DFTs
    __shared__ float Gs[96][6];
    int c = blockIdx.x, t = threadIdx.x;
    if (t < 96) { float a = TWO_PI * (float)t / 96.0f; cs[t][0] = cosf(a); cs[t][1] = sinf(a); }
    float mxv = __uint_as_float(MnMx[c]);
    float mn  = __uint_as_float(MnMx[256 + c]);
    float ptp = mxv - mn;
    __syncthreads();

    // Phase A: thread (xx = t%96, h = t/96) sums 12 rows of the column DFT
    {
        int xx = t % 96, h = t / 96;
        const float* xp = x + c * HW;
        float g0r = 0, g0i = 0, g1r = 0, g1i = 0, g2 = 0;
        for (int y = h * 12; y < h * 12 + 12; ++y) {
            float a = fabsf(xp[y * 96 + xx]);
            float q = floorf(255.0f * (a - mn) / ptp);
            float c1 = cs[y][0], s1 = cs[y][1];
            float c2 = c1 * c1 - s1 * s1, s2 = 2.0f * c1 * s1;
            g0r += q * c2; g0i += q * s2;   // k=-2: e^{+2iθ}
            g1r += q * c1; g1i += q * s1;   // k=-1: e^{+iθ}
            g2  += q;                       // k=0
        }
        Gp[h][xx][0] = g0r; Gp[h][xx][1] = g0i;
        Gp[h][xx][2] = g1r; Gp[h][xx][3] = g1i;
        Gp[h][xx][4] = g2;
    }
    __syncthreads();
    if (t < 96) {
        #pragma unroll
        for (int j = 0; j < 5; ++j) {
            float s = 0.f;
            #pragma unroll
            for (int h = 0; h < 8; ++h) s += Gp[h][t][j];
            Gs[t][j] = s;
        }
        Gs[t][5] = 0.f;
    }
    __syncthreads();
    // Phase A2: 64 threads = 16 coefs x 4 column-quarters, shfl combine
    if (t < 64) {
        int coef = t >> 2, qq = t & 3;
        int ky = coef >> 2, kx = coef & 3;
        float fr = 0, fi = 0;
        for (int xx = qq * 24; xx < qq * 24 + 24; ++xx) {
            float c1 = cs[xx][0], s1 = cs[xx][1];
            float er, ei;
            if (kx == 0)      { er = c1 * c1 - s1 * s1; ei = 2.0f * c1 * s1; }
            else if (kx == 1) { er = c1; ei = s1; }
            else if (kx == 2) { er = 1.f; ei = 0.f; }
            else              { er = c1; ei = -s1; }
            float gr, gi;
            if (ky == 0)      { gr = Gs[xx][0]; gi = Gs[xx][1]; }
            else if (ky == 1) { gr = Gs[xx][2]; gi = Gs[xx][3]; }
            else if (ky == 2) { gr = Gs[xx][4]; gi = 0.f; }
            else              { gr = Gs[xx][2]; gi = -Gs[xx][3]; }
            fr += gr * er - gi * ei;
            fi += gr * ei + gi * er;
        }
        fr += __shfl_xor(fr, 1, 64); fr += __shfl_xor(fr, 2, 64);
        fi += __shfl_xor(fi, 1, 64); fi += __shfl_xor(fi, 2, 64);
        if (qq == 0) {
            Fg[c * 32 + 2 * coef]     = fr;
            Fg[c * 32 + 2 * coef + 1] = fi;
        }
    }
}

// ---------------- K2: synthesis -> FQ bf16 in GEMM tile order [ptile][kc][n] ----------------
__global__ __launch_bounds__(256) void k_synth(const float* __restrict__ Fg,
                                               unsigned short* __restrict__ XTq) {
    int c = threadIdx.x;
    int bx = blockIdx.x;
    int y0 = blockIdx.y * 32;
    float Fr[4][4], Fi[4][4];
    #pragma unroll
    for (int k = 0; k < 16; ++k) {
        Fr[k >> 2][k & 3] = Fg[c * 32 + 2 * k];
        Fi[k >> 2][k & 3] = Fg[c * 32 + 2 * k + 1];
    }
    float ax = TWO_PI * (float)bx / 96.0f;
    float cx = cosf(ax), sx = sinf(ax);
    float cx2 = cx * cx - sx * sx, sx2 = 2.0f * cx * sx;
    float Txr[4] = { cx2, cx, 1.f, cx };
    float Txi[4] = { -sx2, -sx, 0.f, sx };
    float Pr[4], Pi[4];
    #pragma unroll
    for (int ky = 0; ky < 4; ++ky) {
        float pr = 0, pi = 0;
        #pragma unroll
        for (int kx = 0; kx < 4; ++kx) {
            pr += Fr[ky][kx] * Txr[kx] - Fi[ky][kx] * Txi[kx];
            pi += Fr[ky][kx] * Txi[kx] + Fi[ky][kx] * Txr[kx];
        }
        Pr[ky] = pr; Pi[ky] = pi;
    }
    const float inv = 1.0f / 9216.0f;
    for (int y = y0; y < y0 + 32; ++y) {
        float ay = TWO_PI * (float)y / 96.0f;
        float cy = cosf(ay), sy = sinf(ay);
        float cy2 = cy * cy - sy * sy, sy2 = 2.0f * cy * sy;
        float ar =  Pr[0] * cy2 + Pi[0] * sy2 + Pr[1] * cy + Pi[1] * sy + Pr[2] + Pr[3] * cy - Pi[3] * sy;
        float ai = -Pr[0] * sy2 + Pi[0] * cy2 - Pr[1] * sy + Pi[1] * cy + Pi[2] + Pr[3] * sy + Pi[3] * cy;
        float v = sqrtf(ar * ar + ai * ai) * inv;
        int p = y * 96 + bx;
        XTq[(size_t)(((p >> 6) * 2048) + ((c >> 3) * 64) + (p & 63)) * 8 + (c & 7)] = f2bf(v);
    }
}

// ---------------- MFMA GEMM 64x64 tile, K=256 one-shot in LDS ----------------
// EPI=1: Q-GEMM, epilogue = reshape-column-max into FQm (monotone-uint atomicMax).
// EPI=2: V-GEMM, epilogue = out = (V+b) * (1 + decode(FQm[k])).
template<int EPI>
__global__ __launch_bounds__(256) void k_gemm(const short8* __restrict__ Wt,
                                              const short8* __restrict__ Xt,
                                              const float* __restrict__ bias,
                                              unsigned* __restrict__ FQm,
                                              float* __restrict__ out) {
    __shared__ short8 As[2048];   // 32 KB  [kc][m]
    __shared__ short8 Bs[2048];   // 32 KB  [kc][n]
    int tid = threadIdx.x;
    int pt_ = blockIdx.x, ot = blockIdx.y;
    const short8* wsrc = Wt + ot * 2048;
    const short8* xsrc = Xt + pt_ * 2048;
    #pragma unroll
    for (int i = 0; i < 8; ++i) As[i * 256 + tid] = wsrc[i * 256 + tid];
    #pragma unroll
    for (int i = 0; i < 8; ++i) Bs[i * 256 + tid] = xsrc[i * 256 + tid];
    __syncthreads();

    int l = tid & 63, w = tid >> 6;
    int wr = w >> 1, wc = w & 1;
    int l15 = l & 15, quad = l >> 4;
    f32x4 acc[2][2] = {};
    int abase = wr * 32 + l15;
    int bbase = wc * 32 + l15;
    #pragma unroll
    for (int s = 0; s < 8; ++s) {
        int kc = s * 4 + quad;
        short8 a0 = As[kc * 64 + abase];
        short8 a1 = As[kc * 64 + abase + 16];
        short8 b0 = Bs[kc * 64 + bbase];
        short8 b1 = Bs[kc * 64 + bbase + 16];
        acc[0][0] = __builtin_amdgcn_mfma_f32_16x16x32_bf16(a0, b0, acc[0][0], 0, 0, 0);
        acc[0][1] = __builtin_amdgcn_mfma_f32_16x16x32_bf16(a0, b1, acc[0][1], 0, 0, 0);
        acc[1][0] = __builtin_amdgcn_mfma_f32_16x16x32_bf16(a1, b0, acc[1][0], 0, 0, 0);
        acc[1][1] = __builtin_amdgcn_mfma_f32_16x16x32_bf16(a1, b1, acc[1][1], 0, 0, 0);
    }

    // C/D layout: col = lane&15, row = quad*4 + reg
    if (EPI == 1) {
        #pragma unroll
        for (int ni = 0; ni < 2; ++ni) {
            #pragma unroll
            for (int r = 0; r < 4; ++r) {
                int o_lo = ot * 64 + wr * 32 + quad * 4 + r;
                float v = fmaxf(acc[0][ni][r] + bias[o_lo], acc[1][ni][r] + bias[o_lo + 16]);
                v = fmaxf(v, __shfl_xor(v, 32, 64));
                if (quad < 2) {
                    int p = pt_ * 64 + wc * 32 + ni * 16 + l15;
                    int k = ((quad * 4 + r) & 7) * HW + p;
                    if (k >= CW) k -= CW;
                    if (k >= CW) k -= CW;
                    unsigned u = __float_as_uint(v);
                    unsigned key = (u & 0x80000000u) ? ~u : (u | 0x80000000u);
                    atomicMax(&FQm[k], key);
                }
            }
        }
    } else {
        #pragma unroll
        for (int mi = 0; mi < 2; ++mi) {
            #pragma unroll
            for (int ni = 0; ni < 2; ++ni) {
                #pragma unroll
                for (int r = 0; r < 4; ++r) {
                    int o = ot * 64 + wr * 32 + mi * 16 + quad * 4 + r;
                    int p = pt_ * 64 + wc * 32 + ni * 16 + l15;
                    int k = ((quad * 4 + r) & 7) * HW + p;
                    if (k >= CW) k -= CW;
                    if (k >= CW) k -= CW;
                    unsigned key = FQm[k];
                    unsigned ub = (key & 0x80000000u) ? (key ^ 0x80000000u) : ~key;
                    float m = __uint_as_float(ub);
                    float v = acc[mi][ni][r] + bias[o];
                    out[(size_t)o * HW + p] = v * (1.0f + m);
                }
            }
        }
    }
}

extern "C" void kernel_launch(void* const* d_in, const int* in_sizes, int n_in,
                              void* d_out, int out_size, void* d_ws, size_t ws_size,
                              hipStream_t stream) {
    const float* fuse = (const float*)d_in[0];
    const float* Wq   = (const float*)d_in[1];
    const float* bq   = (const float*)d_in[2];
    // d_in[3]=Wk, d_in[4]=bk dead for B=1 (softmax over batch axis of size 1 == 1)
    const float* Wv   = (const float*)d_in[5];
    const float* bv   = (const float*)d_in[6];
    float* out = (float*)d_out;

    char* ws = (char*)d_ws;
    unsigned*       FQm  = (unsigned*)(ws);                  //  98304 B (24576 u32, zero-init)
    unsigned*       MnMx = (unsigned*)(ws + 98304);          //   2048 B (poison-immune atomics)
    float*          Fg   = (float*)(ws + 100352);            //  32768 B
    short8*         Wqt  = (short8*)(ws + 133120);           // 131072 B
    short8*         Wvt  = (short8*)(ws + 264192);           // 131072 B
    unsigned short* XTq  = (unsigned short*)(ws + 395264);   // 4718592 B
    unsigned short* XTv  = (unsigned short*)(ws + 5113856);  // 4718592 B

    hipMemsetAsync(FQm, 0, 98304, stream);
    k_front<<<640, 256, 0, stream>>>(fuse, Wq, Wv, Wqt, Wvt, XTv, MnMx);
    k_dft<<<256, 768, 0, stream>>>(fuse, MnMx, Fg);
    k_synth<<<dim3(96, 3), 256, 0, stream>>>(Fg, XTq);
    k_gemm<1><<<dim3(144, 4), 256, 0, stream>>>(Wqt, (const short8*)XTq, bq, FQm, nullptr);
    k_gemm<2><<<dim3(144, 4), 256, 0, stream>>>(Wvt, (const short8*)XTv, bv, FQm, out);
}

// Round 6
// 117.733 us; speedup vs baseline: 1.3550x; 1.3550x over previous
//
#include <hip/hip_runtime.h>
#include <math.h>

#define CCH 256
#define HW  9216
#define CW  24576
#define TWO_PI 6.28318530717958647692f

typedef __attribute__((ext_vector_type(8))) short short8;
typedef __attribute__((ext_vector_type(4))) float f32x4;

__device__ inline unsigned short f2bf(float f) {
    unsigned u = __float_as_uint(f);
    unsigned r = (u + 0x7FFFu + ((u >> 16) & 1u)) >> 16;   // RNE
    return (unsigned short)r;
}

// ---------------- K_front: fused transp (+minmax partials), wconv, FQm zeroing ----------------
// blocks [0,576): fuse -> bf16 tiles [ptile][kc][n]; per-(channel,ptile) |x| min/max partials
// blocks [576,640): Wq/Wv -> bf16 tiles [ot][kc][m]; each zeroes 384 words of FQm
__global__ __launch_bounds__(256) void k_front(const float* __restrict__ x,
                                               const float* __restrict__ Wq,
                                               const float* __restrict__ Wv,
                                               short8* __restrict__ Wqt,
                                               short8* __restrict__ Wvt,
                                               unsigned short* __restrict__ XTv,
                                               float* __restrict__ PartLo,
                                               float* __restrict__ PartHi,
                                               unsigned* __restrict__ FQm) {
    __shared__ unsigned short lt[64][66];
    __shared__ float sabs[64][65];
    __shared__ float slo[64][4], shi[64][4];
    int bid = blockIdx.x;
    int t = threadIdx.x;
    if (bid < 576) {
        int ptile = bid % 144, ct = bid / 144;
        int tx = t & 63, tw = t >> 6;
        int p0 = ptile * 64, c0 = ct * 64;
        #pragma unroll
        for (int i = 0; i < 16; ++i) {
            int row = tw * 16 + i;
            float v = x[(size_t)(c0 + row) * HW + p0 + tx];
            lt[row][tx] = f2bf(v);
            sabs[row][tx] = fabsf(v);
        }
        __syncthreads();
        // per-row min/max: level 1 — thread (row=t>>2, seg=t&3) scans 16 values
        {
            int row = t >> 2, seg = t & 3;
            float lo = sabs[row][seg * 16], hi = lo;
            #pragma unroll
            for (int j = 1; j < 16; ++j) {
                float a = sabs[row][seg * 16 + j];
                lo = fminf(lo, a);
                hi = fmaxf(hi, a);
            }
            slo[row][seg] = lo; shi[row][seg] = hi;
        }
        // phase 2: tile shuffle to [kc][n] chunk order (needs only lt)
        short8* dst = (short8*)XTv;
        __syncthreads();
        if (t < 64) {
            float lo = fminf(fminf(slo[t][0], slo[t][1]), fminf(slo[t][2], slo[t][3]));
            float hi = fmaxf(fmaxf(shi[t][0], shi[t][1]), fmaxf(shi[t][2], shi[t][3]));
            PartLo[(size_t)(c0 + t) * 144 + ptile] = lo;
            PartHi[(size_t)(c0 + t) * 144 + ptile] = hi;
        }
        #pragma unroll
        for (int ch = 0; ch < 2; ++ch) {
            int lc = ch * 256 + t;
            int kcg = lc >> 6, n = lc & 63;
            short8 v;
            #pragma unroll
            for (int e = 0; e < 8; ++e) v[e] = (short)lt[kcg * 8 + e][n];
            dst[ptile * 2048 + (ct * 8 + kcg) * 64 + n] = v;
        }
    } else {
        int widx = bid - 576;                         // 0..63
        // zero FQm: 64 blocks x 384 words
        int z0 = widx * 384;
        FQm[z0 + t] = 0u;
        if (t < 128) FQm[z0 + 256 + t] = 0u;
        const float* src = (widx >= 32) ? Wv : Wq;
        short8* dst = (widx >= 32) ? Wvt : Wqt;
        int cidx = (widx & 31) * 256 + t;             // 0..8191
        int ot = cidx >> 11, kc = (cidx >> 6) & 31, m = cidx & 63;
        const float* s = src + (ot * 64 + m) * 256 + kc * 8;
        short8 v;
        #pragma unroll
        for (int e = 0; e < 8; ++e) v[e] = (short)f2bf(s[e]);
        dst[cidx] = v;
    }
}

// ---------------- K1: 16 DFT coefficients per channel ----------------
// Prologue reduces the 144 min/max partials; then column DFTs as before.
__global__ __launch_bounds__(768) void k_dft(const float* __restrict__ x,
                                             const float* __restrict__ PartLo,
                                             const float* __restrict__ PartHi,
                                             float* __restrict__ Fg) {
    __shared__ float cs[96][2];
    __shared__ float Gp[8][96][5];
    __shared__ float Gs[96][6];
    __shared__ float s_mn, s_ptp;
    int c = blockIdx.x, t = threadIdx.x;
    if (t < 96) { float a = TWO_PI * (float)t / 96.0f; cs[t][0] = cosf(a); cs[t][1] = sinf(a); }
    if (t >= 128 && t < 192) {
        int u = t - 128;
        float lo = 1e30f, hi = 0.f;
        for (int i = u; i < 144; i += 64) {
            lo = fminf(lo, PartLo[(size_t)c * 144 + i]);
            hi = fmaxf(hi, PartHi[(size_t)c * 144 + i]);
        }
        #pragma unroll
        for (int d = 32; d; d >>= 1) {
            lo = fminf(lo, __shfl_xor(lo, d, 64));
            hi = fmaxf(hi, __shfl_xor(hi, d, 64));
        }
        if (u == 0) { s_mn = lo; s_ptp = hi - lo; }
    }
    __syncthreads();
    float mn = s_mn, ptp = s_ptp;

    // Phase A: thread (xx = t%96, h = t/96) sums 12 rows of the column DFT
    {
        int xx = t % 96, h = t / 96;
        const float* xp = x + c * HW;
        float g0r = 0, g0i = 0, g1r = 0, g1i = 0, g2 = 0;
        for (int y = h * 12; y < h * 12 + 12; ++y) {
            float a = fabsf(xp[y * 96 + xx]);
            float q = floorf(255.0f * (a - mn) / ptp);
            float c1 = cs[y][0], s1 = cs[y][1];
            float c2 = c1 * c1 - s1 * s1, s2 = 2.0f * c1 * s1;
            g0r += q * c2; g0i += q * s2;   // k=-2: e^{+2iθ}
            g1r += q * c1; g1i += q * s1;   // k=-1: e^{+iθ}
            g2  += q;                       // k=0
        }
        Gp[h][xx][0] = g0r; Gp[h][xx][1] = g0i;
        Gp[h][xx][2] = g1r; Gp[h][xx][3] = g1i;
        Gp[h][xx][4] = g2;
    }
    __syncthreads();
    if (t < 96) {
        #pragma unroll
        for (int j = 0; j < 5; ++j) {
            float s = 0.f;
            #pragma unroll
            for (int h = 0; h < 8; ++h) s += Gp[h][t][j];
            Gs[t][j] = s;
        }
        Gs[t][5] = 0.f;
    }
    __syncthreads();
    if (t < 64) {
        int coef = t >> 2, qq = t & 3;
        int ky = coef >> 2, kx = coef & 3;
        float fr = 0, fi = 0;
        for (int xx = qq * 24; xx < qq * 24 + 24; ++xx) {
            float c1 = cs[xx][0], s1 = cs[xx][1];
            float er, ei;
            if (kx == 0)      { er = c1 * c1 - s1 * s1; ei = 2.0f * c1 * s1; }
            else if (kx == 1) { er = c1; ei = s1; }
            else if (kx == 2) { er = 1.f; ei = 0.f; }
            else              { er = c1; ei = -s1; }
            float gr, gi;
            if (ky == 0)      { gr = Gs[xx][0]; gi = Gs[xx][1]; }
            else if (ky == 1) { gr = Gs[xx][2]; gi = Gs[xx][3]; }
            else if (ky == 2) { gr = Gs[xx][4]; gi = 0.f; }
            else              { gr = Gs[xx][2]; gi = -Gs[xx][3]; }
            fr += gr * er - gi * ei;
            fi += gr * ei + gi * er;
        }
        fr += __shfl_xor(fr, 1, 64); fr += __shfl_xor(fr, 2, 64);
        fi += __shfl_xor(fi, 1, 64); fi += __shfl_xor(fi, 2, 64);
        if (qq == 0) {
            Fg[c * 32 + 2 * coef]     = fr;
            Fg[c * 32 + 2 * coef + 1] = fi;
        }
    }
}

// ---------------- K2: synthesis -> FQ bf16 in GEMM tile order [ptile][kc][n] ----------------
__global__ __launch_bounds__(256) void k_synth(const float* __restrict__ Fg,
                                               unsigned short* __restrict__ XTq) {
    int c = threadIdx.x;
    int bx = blockIdx.x;
    int y0 = blockIdx.y * 32;
    float Fr[4][4], Fi[4][4];
    #pragma unroll
    for (int k = 0; k < 16; ++k) {
        Fr[k >> 2][k & 3] = Fg[c * 32 + 2 * k];
        Fi[k >> 2][k & 3] = Fg[c * 32 + 2 * k + 1];
    }
    float ax = TWO_PI * (float)bx / 96.0f;
    float cx = cosf(ax), sx = sinf(ax);
    float cx2 = cx * cx - sx * sx, sx2 = 2.0f * cx * sx;
    float Txr[4] = { cx2, cx, 1.f, cx };
    float Txi[4] = { -sx2, -sx, 0.f, sx };
    float Pr[4], Pi[4];
    #pragma unroll
    for (int ky = 0; ky < 4; ++ky) {
        float pr = 0, pi = 0;
        #pragma unroll
        for (int kx = 0; kx < 4; ++kx) {
            pr += Fr[ky][kx] * Txr[kx] - Fi[ky][kx] * Txi[kx];
            pi += Fr[ky][kx] * Txi[kx] + Fi[ky][kx] * Txr[kx];
        }
        Pr[ky] = pr; Pi[ky] = pi;
    }
    const float inv = 1.0f / 9216.0f;
    for (int y = y0; y < y0 + 32; ++y) {
        float ay = TWO_PI * (float)y / 96.0f;
        float cy = cosf(ay), sy = sinf(ay);
        float cy2 = cy * cy - sy * sy, sy2 = 2.0f * cy * sy;
        float ar =  Pr[0] * cy2 + Pi[0] * sy2 + Pr[1] * cy + Pi[1] * sy + Pr[2] + Pr[3] * cy - Pi[3] * sy;
        float ai = -Pr[0] * sy2 + Pi[0] * cy2 - Pr[1] * sy + Pi[1] * cy + Pi[2] + Pr[3] * sy + Pi[3] * cy;
        float v = sqrtf(ar * ar + ai * ai) * inv;
        int p = y * 96 + bx;
        XTq[(size_t)(((p >> 6) * 2048) + ((c >> 3) * 64) + (p & 63)) * 8 + (c & 7)] = f2bf(v);
    }
}

// ---------------- MFMA GEMM 64x64 tile, K=256 one-shot in LDS ----------------
template<int EPI>
__global__ __launch_bounds__(256) void k_gemm(const short8* __restrict__ Wt,
                                              const short8* __restrict__ Xt,
                                              const float* __restrict__ bias,
                                              unsigned* __restrict__ FQm,
                                              float* __restrict__ out) {
    __shared__ short8 As[2048];   // 32 KB  [kc][m]
    __shared__ short8 Bs[2048];   // 32 KB  [kc][n]
    int tid = threadIdx.x;
    int pt_ = blockIdx.x, ot = blockIdx.y;
    const short8* wsrc = Wt + ot * 2048;
    const short8* xsrc = Xt + pt_ * 2048;
    #pragma unroll
    for (int i = 0; i < 8; ++i) As[i * 256 + tid] = wsrc[i * 256 + tid];
    #pragma unroll
    for (int i = 0; i < 8; ++i) Bs[i * 256 + tid] = xsrc[i * 256 + tid];
    __syncthreads();

    int l = tid & 63, w = tid >> 6;
    int wr = w >> 1, wc = w & 1;
    int l15 = l & 15, quad = l >> 4;
    f32x4 acc[2][2] = {};
    int abase = wr * 32 + l15;
    int bbase = wc * 32 + l15;
    #pragma unroll
    for (int s = 0; s < 8; ++s) {
        int kc = s * 4 + quad;
        short8 a0 = As[kc * 64 + abase];
        short8 a1 = As[kc * 64 + abase + 16];
        short8 b0 = Bs[kc * 64 + bbase];
        short8 b1 = Bs[kc * 64 + bbase + 16];
        acc[0][0] = __builtin_amdgcn_mfma_f32_16x16x32_bf16(a0, b0, acc[0][0], 0, 0, 0);
        acc[0][1] = __builtin_amdgcn_mfma_f32_16x16x32_bf16(a0, b1, acc[0][1], 0, 0, 0);
        acc[1][0] = __builtin_amdgcn_mfma_f32_16x16x32_bf16(a1, b0, acc[1][0], 0, 0, 0);
        acc[1][1] = __builtin_amdgcn_mfma_f32_16x16x32_bf16(a1, b1, acc[1][1], 0, 0, 0);
    }

    // C/D layout: col = lane&15, row = quad*4 + reg
    if (EPI == 1) {
        #pragma unroll
        for (int ni = 0; ni < 2; ++ni) {
            #pragma unroll
            for (int r = 0; r < 4; ++r) {
                int o_lo = ot * 64 + wr * 32 + quad * 4 + r;
                float v = fmaxf(acc[0][ni][r] + bias[o_lo], acc[1][ni][r] + bias[o_lo + 16]);
                v = fmaxf(v, __shfl_xor(v, 32, 64));
                if (quad < 2) {
                    int p = pt_ * 64 + wc * 32 + ni * 16 + l15;
                    int k = ((quad * 4 + r) & 7) * HW + p;
                    if (k >= CW) k -= CW;
                    if (k >= CW) k -= CW;
                    unsigned u = __float_as_uint(v);
                    unsigned key = (u & 0x80000000u) ? ~u : (u | 0x80000000u);
                    atomicMax(&FQm[k], key);
                }
            }
        }
    } else {
        #pragma unroll
        for (int mi = 0; mi < 2; ++mi) {
            #pragma unroll
            for (int ni = 0; ni < 2; ++ni) {
                #pragma unroll
                for (int r = 0; r < 4; ++r) {
                    int o = ot * 64 + wr * 32 + mi * 16 + quad * 4 + r;
                    int p = pt_ * 64 + wc * 32 + ni * 16 + l15;
                    int k = ((quad * 4 + r) & 7) * HW + p;
                    if (k >= CW) k -= CW;
                    if (k >= CW) k -= CW;
                    unsigned key = FQm[k];
                    unsigned ub = (key & 0x80000000u) ? (key ^ 0x80000000u) : ~key;
                    float m = __uint_as_float(ub);
                    float v = acc[mi][ni][r] + bias[o];
                    out[(size_t)o * HW + p] = v * (1.0f + m);
                }
            }
        }
    }
}

extern "C" void kernel_launch(void* const* d_in, const int* in_sizes, int n_in,
                              void* d_out, int out_size, void* d_ws, size_t ws_size,
                              hipStream_t stream) {
    const float* fuse = (const float*)d_in[0];
    const float* Wq   = (const float*)d_in[1];
    const float* bq   = (const float*)d_in[2];
    // d_in[3]=Wk, d_in[4]=bk dead for B=1 (softmax over batch axis of size 1 == 1)
    const float* Wv   = (const float*)d_in[5];
    const float* bv   = (const float*)d_in[6];
    float* out = (float*)d_out;

    char* ws = (char*)d_ws;
    unsigned*       FQm    = (unsigned*)(ws);                //  98304 B (zeroed by k_front)
    float*          Fg     = (float*)(ws + 98304);           //  32768 B
    short8*         Wqt    = (short8*)(ws + 131072);         // 131072 B
    short8*         Wvt    = (short8*)(ws + 262144);         // 131072 B
    float*          PartLo = (float*)(ws + 393216);          // 147456 B (256 x 144)
    float*          PartHi = (float*)(ws + 540672);          // 147456 B
    unsigned short* XTq    = (unsigned short*)(ws + 688128); // 4718592 B
    unsigned short* XTv    = (unsigned short*)(ws + 5406720);// 4718592 B

    k_front<<<640, 256, 0, stream>>>(fuse, Wq, Wv, Wqt, Wvt, XTv, PartLo, PartHi, FQm);
    k_dft<<<256, 768, 0, stream>>>(fuse, PartLo, PartHi, Fg);
    k_synth<<<dim3(96, 3), 256, 0, stream>>>(Fg, XTq);
    k_gemm<1><<<dim3(144, 4), 256, 0, stream>>>(Wqt, (const short8*)XTq, bq, FQm, nullptr);
    k_gemm<2><<<dim3(144, 4), 256, 0, stream>>>(Wvt, (const short8*)XTv, bv, FQm, out);
}